// Round 14
// baseline (103.089 us; speedup 1.0000x reference)
//
#include <hip/hip_runtime.h>
#include <stdint.h>

// AdaMoLE R14 = R13 with k1 COLUMN-SPLIT: grid 512 = 256 tok-grps x 2
// col-halves, 1024 thr. Wave (t_=w&3, q=w>>2): col-tile half*4+t_, k32
// residues q (mod 4). Gating tile-8 computed redundantly per half (no
// cross-block dep). Sync structure byte-identical to R10/R13's proven
// 2-barrier loop. LDS 71 KB + avA/avB split prefetch targets VGPR<=64
// -> 2 blocks/CU -> 32 waves/CU (was 16).
//  Global wh layout is BIT-IDENTICAL to R10's (XOR (tok&7)<<4 only touches
//  bits 4-6; 128-B col-halves never mix) -> k2_out unchanged.
//  k2_out / pack_all: proven kernels, unchanged.
//
//  ws: W1p frag-major 1,179,648 B | B2p frag-major 1,048,576 B | wh 2 MB

typedef __bf16 bf16x8 __attribute__((ext_vector_type(8)));
typedef float f32x4 __attribute__((ext_vector_type(4)));
typedef __attribute__((address_space(1))) const void* gp_t;
typedef __attribute__((address_space(3))) void* lp_t;

__device__ __forceinline__ f32x4 mfma16(bf16x8 a, bf16x8 b, f32x4 c) {
  return __builtin_amdgcn_mfma_f32_16x16x32_bf16(a, b, c, 0, 0, 0);
}
__device__ __forceinline__ uint32_t bfbits(float f) {
  uint32_t u = __builtin_bit_cast(uint32_t, f);
  return (u + 0x7fffu + ((u >> 16) & 1u)) >> 16;
}
__device__ __forceinline__ uint32_t pk2(float a, float b) {
  return bfbits(a) | (bfbits(b) << 16);
}

// LDS-only barrier (proven R10/R13): lgkmcnt drained, global ops stream on.
#define LDS_BARRIER() do {                                   \
    asm volatile("s_waitcnt lgkmcnt(0)" ::: "memory");       \
    __builtin_amdgcn_sched_barrier(0);                       \
    __builtin_amdgcn_s_barrier();                            \
    __builtin_amdgcn_sched_barrier(0);                       \
  } while (0)

// ---------------- merged pack: blocks [0,288) = W1p, [288,544) = B2p.
// W1p rows ct*16+(l&15): 0..127 lora_A (row=e*16+r), 128..135 router_w,
// 136 thr_w, 137..143 zero. B2p: SCALING=2 folded.
__global__ void pack_all(const float* __restrict__ rw, const float* __restrict__ tw,
                         const float* __restrict__ la, const float* __restrict__ lb,
                         uint4* __restrict__ W1p, uint4* __restrict__ B2p) {
  if (blockIdx.x < 288) {
    int id = blockIdx.x * 256 + threadIdx.x;          // 9*128*64 = 73728
    int lane = id & 63, k32 = (id >> 6) & 127, ct = id >> 13;
    int row = ct * 16 + (lane & 15);
    int col = k32 * 32 + (lane >> 4) * 8;
    const float* src = nullptr;
    if (row < 128)      src = la + (size_t)row * 4096 + col;
    else if (row < 136) src = rw + (size_t)(row - 128) * 4096 + col;
    else if (row == 136) src = tw + col;
    float v[8];
#pragma unroll
    for (int j = 0; j < 8; ++j) v[j] = src ? src[j] : 0.f;
    uint4 u;
    u.x = pk2(v[0], v[1]); u.y = pk2(v[2], v[3]);
    u.z = pk2(v[4], v[5]); u.w = pk2(v[6], v[7]);
    W1p[(size_t)(ct * 128 + k32) * 64 + lane] = u;
  } else {
    int id = (blockIdx.x - 288) * 256 + threadIdx.x;  // 256*4*64 = 65536
    int lane = id & 63, ks = (id >> 6) & 3, ct = id >> 8;
    int o = ct * 16 + (lane & 15);
    int k0 = ks * 32 + (lane >> 4) * 8;
    const float* s = lb + (size_t)(k0 >> 4) * 65536 + (size_t)o * 16 + (k0 & 15);
    uint4 u;
    u.x = pk2(s[0] * 2.f, s[1] * 2.f); u.y = pk2(s[2] * 2.f, s[3] * 2.f);
    u.z = pk2(s[4] * 2.f, s[5] * 2.f); u.w = pk2(s[6] * 2.f, s[7] * 2.f);
    B2p[(size_t)(ct * 4 + ks) * 64 + lane] = u;
  }
}

// ---------------- k1_gate: 32 tok x 64 cols per block, 16 waves, grid 512.
__global__ __launch_bounds__(1024) void k1_gate(
    const float* __restrict__ inp, const uint4* __restrict__ W1p,
    const float* __restrict__ rb, const float* __restrict__ tb,
    unsigned short* __restrict__ wh) {
  // [0,64K): A tile 32 rows x 2048B = one 1024-k chunk (single-buffered);
  //          reductions reuse: accO slots [0,32K), acc8 slots [32K,64K).
  // [65536,+4K): whl bf16 [32][64] swizzled (this block's col-half).
  // [69632,+2K): scores[32][16]. [71680,+1K): wgt[32][8].  total 72704 B.
  __shared__ __align__(16) char smem[72704];
  char* const Ab  = smem;
  char* const whl = smem + 65536;
  float* const scores = (float*)(smem + 69632);
  float* const wgt    = (float*)(smem + 71680);

  const int t = threadIdx.x;           // 0..1023
  const int lane = t & 63;
  const int w = t >> 6;                // 0..15
  const int t_ = w & 3;                // tile within half
  const int q  = w >> 2;               // k32 residue (mod 4)
  const int l15 = lane & 15;
  const int lq = lane >> 4;
  const int tokg = blockIdx.x >> 1;
  const int half = blockIdx.x & 1;
  const int n0 = tokg * 32;
  const int ct_ = half * 4 + t_;       // global col-tile 0..7
  const int rx = (l15 & 7) << 4;

  // A staging: 1024 thr x 32 floats = 32 rows x 1024 k per chunk.
  const int srow = t >> 5;             // 0..31
  const int scf = t & 31;              // fp32 cols scf*4 + j*128
  const float* ap = inp + (size_t)(n0 + srow) * 4096 + scf * 4;
  const int sx = (srow & 7) << 4;

  f32x4 accO[2] = {}, acc8[2] = {};
  float4 avA[4], avB[4];

  const uint4* wown = W1p + (size_t)(ct_ * 128) * 64 + lane;
  const uint4* w8b  = W1p + (size_t)(8 * 128) * 64 + lane;

  // ---- prologue: stage chunk 0
#pragma unroll
  for (int j = 0; j < 4; ++j) avA[j] = *(const float4*)(ap + j * 128);
#pragma unroll
  for (int j = 0; j < 4; ++j) avB[j] = *(const float4*)(ap + (j + 4) * 128);
  {
    char* d2 = Ab + srow * 2048;
#pragma unroll
    for (int j = 0; j < 4; ++j) {
      uint2 u; u.x = pk2(avA[j].x, avA[j].y); u.y = pk2(avA[j].z, avA[j].w);
      *(uint2*)(d2 + ((scf * 8 + j * 256) ^ sx)) = u;
    }
#pragma unroll
    for (int j = 0; j < 4; ++j) {
      uint2 u; u.x = pk2(avB[j].x, avB[j].y); u.y = pk2(avB[j].z, avB[j].w);
      *(uint2*)(d2 + ((scf * 8 + (j + 4) * 256) ^ sx)) = u;
    }
  }
  LDS_BARRIER();

  for (int c = 0; c < 4; ++c) {        // 4 chunks of 1024 k
    if (c < 3) {  // prefetch group A early (covers main MFMA phase)
#pragma unroll
      for (int j = 0; j < 4; ++j)
        avA[j] = *(const float4*)(ap + (size_t)(c + 1) * 1024 + j * 128);
    }
    // main: 8 k32-slots (residue q) x 2 row-halves
#pragma unroll
    for (int s = 0; s < 8; ++s) {
      const int kl = s * 4 + q;        // k32 slot within chunk, 0..31
      bf16x8 b = __builtin_bit_cast(bf16x8, wown[(size_t)(c * 32 + kl) * 64]);
      bf16x8 a0 = *(const bf16x8*)(Ab + l15 * 2048 + ((kl * 64 + lq * 16) ^ rx));
      bf16x8 a1 = *(const bf16x8*)(Ab + (16 + l15) * 2048 + ((kl * 64 + lq * 16) ^ rx));
      accO[0] = mfma16(a0, b, accO[0]);
      accO[1] = mfma16(a1, b, accO[1]);
    }
    if (c < 3) {  // prefetch group B mid (keeps peak VGPR low)
#pragma unroll
      for (int j = 0; j < 4; ++j)
        avB[j] = *(const float4*)(ap + (size_t)(c + 1) * 1024 + (j + 4) * 128);
    }
    // gating tile-8: 2 slots per wave; (t_,i,q) covers all 32 slots once
#pragma unroll
    for (int i = 0; i < 2; ++i) {
      const int ks8 = (2 * t_ + i) * 4 + q;
      bf16x8 b8 = __builtin_bit_cast(bf16x8, w8b[(size_t)(c * 32 + ks8) * 64]);
      bf16x8 a0 = *(const bf16x8*)(Ab + l15 * 2048 + ((ks8 * 64 + lq * 16) ^ rx));
      bf16x8 a1 = *(const bf16x8*)(Ab + (16 + l15) * 2048 + ((ks8 * 64 + lq * 16) ^ rx));
      acc8[0] = mfma16(a0, b8, acc8[0]);
      acc8[1] = mfma16(a1, b8, acc8[1]);
    }
    if (c < 3) {
      LDS_BARRIER();                   // all reads of Ab done
      char* d2 = Ab + srow * 2048;
#pragma unroll
      for (int j = 0; j < 4; ++j) {
        uint2 u; u.x = pk2(avA[j].x, avA[j].y); u.y = pk2(avA[j].z, avA[j].w);
        *(uint2*)(d2 + ((scf * 8 + j * 256) ^ sx)) = u;
      }
#pragma unroll
      for (int j = 0; j < 4; ++j) {
        uint2 u; u.x = pk2(avB[j].x, avB[j].y); u.y = pk2(avB[j].z, avB[j].w);
        *(uint2*)(d2 + ((scf * 8 + (j + 4) * 256) ^ sx)) = u;
      }
    }
    LDS_BARRIER();                     // staged writes visible / final fence
  }

  // ---- reductions: accO 4-way (q partials) + acc8 16-way (reuse A region)
  *(f32x4*)(Ab + (size_t)((w * 2 + 0) * 64 + lane) * 16) = accO[0];
  *(f32x4*)(Ab + (size_t)((w * 2 + 1) * 64 + lane) * 16) = accO[1];
  *(f32x4*)(Ab + 32768 + (size_t)((w * 2 + 0) * 64 + lane) * 16) = acc8[0];
  *(f32x4*)(Ab + 32768 + (size_t)((w * 2 + 1) * 64 + lane) * 16) = acc8[1];
  LDS_BARRIER();
  f32x4 hO[2] = {};
  if (w < 4) {  // wave w sums tile t_=w over q=0..3 (slots w+4q)
#pragma unroll
    for (int tt = 0; tt < 2; ++tt) {
#pragma unroll
      for (int qq = 0; qq < 4; ++qq) {
        f32x4 x = *(const f32x4*)(Ab + (size_t)(((w + 4 * qq) * 2 + tt) * 64 + lane) * 16);
#pragma unroll
        for (int r_ = 0; r_ < 4; ++r_) hO[tt][r_] += x[r_];
      }
    }
  }
  if (t < 512) {  // gating scores: 32 tok x 16 cols (16-way acc8 reduce)
    const int tok = t >> 4, col = t & 15;
    const int tt = tok >> 4, lq_ = (tok >> 2) & 3, r_ = tok & 3;
    float sv = 0.f;
#pragma unroll
    for (int w2 = 0; w2 < 16; ++w2)
      sv += *(const float*)(Ab + 32768 +
            (size_t)((w2 * 2 + tt) * 64 + lq_ * 16 + col) * 16 + r_ * 4);
    scores[tok * 16 + col] = sv;
  }
  LDS_BARRIER();
  if (t < 32) {
    float l_[9];
#pragma unroll
    for (int e = 0; e < 9; ++e) l_[e] = scores[t * 16 + e];
    float mx = -3.4e38f;
#pragma unroll
    for (int e = 0; e < 8; ++e) { l_[e] += rb[e]; mx = fmaxf(mx, l_[e]); }
    float g[8], s = 0.f;
#pragma unroll
    for (int e = 0; e < 8; ++e) { g[e] = __expf(l_[e] - mx); s += g[e]; }
    const float thr = 0.125f / (1.f + __expf(-(l_[8] + tb[0])));
    const float inv = 1.f / s;
    float wv[8], ws = 0.f;
#pragma unroll
    for (int e = 0; e < 8; ++e) { wv[e] = fmaxf(g[e] * inv - thr, 0.f); ws += wv[e]; }
    const float wn = (ws == 0.f) ? 1.f : ws;
#pragma unroll
    for (int e = 0; e < 8; ++e) wgt[t * 8 + e] = wv[e] / wn;
  }
  LDS_BARRIER();
  // weighted h -> whl [32][64] (wave w<4 == tile w; global expert half*4+w)
  if (w < 4) {
#pragma unroll
    for (int tt = 0; tt < 2; ++tt)
#pragma unroll
      for (int r_ = 0; r_ < 4; ++r_) {
        const int tok = tt * 16 + lq * 4 + r_;
        *(unsigned short*)(whl + tok * 128 + (((w * 16 + l15) * 2) ^ ((tok & 7) << 4))) =
            (unsigned short)bfbits(hO[tt][r_] * wgt[tok * 8 + half * 4 + w]);
      }
  }
  LDS_BARRIER();
  // coalesced wh write of this block's column half (byte-verbatim rows;
  // layout identical to R10's full-row version since XOR stays in bits 4-6)
  if (t < 256) {
    const int row = t >> 3, seg = t & 7;
    ((uint4*)(wh + (size_t)(n0 + row) * 128 + half * 64))[seg] =
        ((const uint4*)(whl + row * 128))[seg];
  }
}

// ---------------- k2_out: out[256 tok][128 col] per block, grid 1024, 512
// thr. B2p slice staged once to LDS; swizzled Ob bounce -> 128B-contiguous
// nontemporal stores; bounce barriers lgkm-only so stores keep streaming.
__global__ __launch_bounds__(512, 4) void k2_out(
    const unsigned short* __restrict__ wh, const uint4* __restrict__ B2p,
    float* __restrict__ out) {
  __shared__ __align__(16) char Bl[32768];
  __shared__ __align__(16) char Ob[32768];
  const int t = threadIdx.x, lane = t & 63, w = t >> 6;
  const int l15 = lane & 15, lq = lane >> 4;
  const int bid = blockIdx.x;
  const int tokg = bid >> 5, colg = bid & 31;
  const int n0 = tokg * 256, c0 = colg * 128;

  {  // stage B slice: 8 ct x 4 ks x 64 lanes x 16B = 32 KB, linear
    const uint4* src = B2p + (size_t)(colg * 32) * 64;
#pragma unroll
    for (int i = 0; i < 4; ++i)
      __builtin_amdgcn_global_load_lds((gp_t)(const void*)(src + i * 512 + t),
          (lp_t)(void*)(Bl + (i * 512 + w * 64) * 16), 16, 0, 0);
  }
  __syncthreads();  // vmcnt drain required (global_load_lds) — keep full sync

  const int srow = t >> 3, sseg = t & 7;       // store map: 64 rows x 8 segs
  const int swz = (srow & 7) << 4;

#pragma unroll
  for (int tt = 0; tt < 2; ++tt) {
    const int tok = n0 + tt * 128 + w * 16 + l15;
    bf16x8 pa[4];
    const uint4* whu = (const uint4*)wh + (size_t)tok * 16;
#pragma unroll
    for (int ks = 0; ks < 4; ++ks)
      pa[ks] = __builtin_bit_cast(bf16x8, whu[(ks * 4 + lq) ^ (l15 & 7)]);
    f32x4 acc[8] = {};
#pragma unroll
    for (int ct = 0; ct < 8; ++ct)
#pragma unroll
      for (int ks = 0; ks < 4; ++ks) {
        bf16x8 b = *(const bf16x8*)(Bl + (size_t)((ct * 4 + ks) * 64 + lane) * 16);
        acc[ct] = mfma16(b, pa[ks], acc[ct]);  // swapped: 4 consecutive cols/lane
      }
#pragma unroll
    for (int sr = 0; sr < 2; ++sr) {
      if ((w >> 2) == sr) {
        const int tl = (w & 3) * 16 + l15;     // 0..63
        char* d = Ob + tl * 512;
#pragma unroll
        for (int ct = 0; ct < 8; ++ct)
          *(f32x4*)(d + ((ct * 64 + lq * 16) ^ ((tl & 7) << 4))) = acc[ct];
      }
      LDS_BARRIER();                           // Ob writes visible; global
                                               // stores keep streaming
      {
        float* op = out + (size_t)(n0 + tt * 128 + sr * 64 + srow) * 4096 + c0 + sseg * 4;
#pragma unroll
        for (int j = 0; j < 4; ++j) {
          f32x4 v = *(const f32x4*)(Ob + srow * 512 + ((sseg * 16 + j * 128) ^ swz));
          __builtin_nontemporal_store(v, (f32x4*)(op + j * 32));
        }
      }
      LDS_BARRIER();                           // Ob reads done before overwrite
    }
  }
}

extern "C" void kernel_launch(void* const* d_in, const int* in_sizes, int n_in,
                              void* d_out, int out_size, void* d_ws, size_t ws_size,
                              hipStream_t stream) {
  (void)in_sizes; (void)n_in; (void)out_size; (void)ws_size;
  const float* inp      = (const float*)d_in[0];
  const float* router_w = (const float*)d_in[1];
  const float* router_b = (const float*)d_in[2];
  const float* thr_w    = (const float*)d_in[3];
  const float* thr_b    = (const float*)d_in[4];
  const float* lora_A   = (const float*)d_in[5];
  const float* lora_B   = (const float*)d_in[6];
  float* out = (float*)d_out;

  char* ws = (char*)d_ws;
  uint4*          W1p = (uint4*)ws;                                // 1,179,648 B
  uint4*          B2p = (uint4*)(ws + 1179648);                    // 1,048,576 B
  unsigned short* wh  = (unsigned short*)(ws + 1179648 + 1048576); // 2,097,152 B

  pack_all<<<544, 256, 0, stream>>>(router_w, thr_w, lora_A, lora_B, W1p, B2p);
  k1_gate<<<512, 1024, 0, stream>>>(inp, W1p, router_b, thr_b, wh);
  k2_out<<<1024, 512, 0, stream>>>(wh, B2p, out);
}

// Round 15
// 66.543 us; speedup vs baseline: 1.5492x; 1.5492x over previous
//
#include <hip/hip_runtime.h>
#include <stdint.h>

// AdaMoLE R15 = exact revert to the R10 champion (66.7 us measured).
//  R14's column-split REVERTED: it doubled A HBM traffic (FETCH 70->136 MB,
//  1.7 TB/s) with zero occupancy gain. R10 shape is the measured optimum:
//   k1_gate: 32 tok/block, 16 waves, grid 256, K-chunk 512, single-buffered
//            A tile, 2-barrier loop (in-loop barriers lgkm-only).
//   k2_out : B2p->LDS once per [256 tok x 128 col] block; swizzled Ob
//            bounce -> 128B-contiguous nontemporal stores (at write floor).
//   pack_all: merged W1p/B2p repack.
//
//  ws: W1p frag-major 1,179,648 B | B2p frag-major 1,048,576 B | wh 2 MB
//  wh[tok][128] bf16 rows carry the (tok&7)<<4 byte-XOR swizzle; k2_out
//  unswizzles via uint4-idx XOR (l15&7).

typedef __bf16 bf16x8 __attribute__((ext_vector_type(8)));
typedef float f32x4 __attribute__((ext_vector_type(4)));
typedef __attribute__((address_space(1))) const void* gp_t;
typedef __attribute__((address_space(3))) void* lp_t;

__device__ __forceinline__ f32x4 mfma16(bf16x8 a, bf16x8 b, f32x4 c) {
  return __builtin_amdgcn_mfma_f32_16x16x32_bf16(a, b, c, 0, 0, 0);
}
__device__ __forceinline__ uint32_t bfbits(float f) {
  uint32_t u = __builtin_bit_cast(uint32_t, f);
  return (u + 0x7fffu + ((u >> 16) & 1u)) >> 16;
}
__device__ __forceinline__ uint32_t pk2(float a, float b) {
  return bfbits(a) | (bfbits(b) << 16);
}

// LDS-only barrier: per-wave ds ops drained (lgkmcnt), execution synced,
// but outstanding GLOBAL loads/stores keep streaming (no vmcnt drain).
#define LDS_BARRIER() do {                                   \
    asm volatile("s_waitcnt lgkmcnt(0)" ::: "memory");       \
    __builtin_amdgcn_sched_barrier(0);                       \
    __builtin_amdgcn_s_barrier();                            \
    __builtin_amdgcn_sched_barrier(0);                       \
  } while (0)

// ---------------- merged pack: blocks [0,288) = W1p, [288,544) = B2p.
// W1p rows ct*16+(l&15): 0..127 lora_A (row=e*16+r), 128..135 router_w,
// 136 thr_w, 137..143 zero. B2p: SCALING=2 folded.
__global__ void pack_all(const float* __restrict__ rw, const float* __restrict__ tw,
                         const float* __restrict__ la, const float* __restrict__ lb,
                         uint4* __restrict__ W1p, uint4* __restrict__ B2p) {
  if (blockIdx.x < 288) {
    int id = blockIdx.x * 256 + threadIdx.x;          // 9*128*64 = 73728
    int lane = id & 63, k32 = (id >> 6) & 127, ct = id >> 13;
    int row = ct * 16 + (lane & 15);
    int col = k32 * 32 + (lane >> 4) * 8;
    const float* src = nullptr;
    if (row < 128)      src = la + (size_t)row * 4096 + col;
    else if (row < 136) src = rw + (size_t)(row - 128) * 4096 + col;
    else if (row == 136) src = tw + col;
    float v[8];
#pragma unroll
    for (int j = 0; j < 8; ++j) v[j] = src ? src[j] : 0.f;
    uint4 u;
    u.x = pk2(v[0], v[1]); u.y = pk2(v[2], v[3]);
    u.z = pk2(v[4], v[5]); u.w = pk2(v[6], v[7]);
    W1p[(size_t)(ct * 128 + k32) * 64 + lane] = u;
  } else {
    int id = (blockIdx.x - 288) * 256 + threadIdx.x;  // 256*4*64 = 65536
    int lane = id & 63, ks = (id >> 6) & 3, ct = id >> 8;
    int o = ct * 16 + (lane & 15);
    int k0 = ks * 32 + (lane >> 4) * 8;
    const float* s = lb + (size_t)(k0 >> 4) * 65536 + (size_t)o * 16 + (k0 & 15);
    uint4 u;
    u.x = pk2(s[0] * 2.f, s[1] * 2.f); u.y = pk2(s[2] * 2.f, s[3] * 2.f);
    u.z = pk2(s[4] * 2.f, s[5] * 2.f); u.w = pk2(s[6] * 2.f, s[7] * 2.f);
    B2p[(size_t)(ct * 4 + ks) * 64 + lane] = u;
  }
}

// ---------------- k1_gate: 32 tok/block, 16 waves, grid 256 (R10 structure).
__global__ __launch_bounds__(1024) void k1_gate(
    const float* __restrict__ inp, const uint4* __restrict__ W1p,
    const float* __restrict__ rb, const float* __restrict__ tb,
    unsigned short* __restrict__ wh) {
  // [0,64K): A tile, 2 K-groups x 32 rows x 1024B (single-buffered);
  //          reused for reductions: accO slots [0,32K), acc8 slots [32K,64K).
  // [64K,+8K): whl bf16 [32][128] swizzled. [73728,+2K): scores[32][16].
  // [75776,+1K): wgt[32][8].
  __shared__ __align__(16) char smem[76800];
  char* const Ab  = smem;
  char* const whl = smem + 65536;
  float* const scores = (float*)(smem + 73728);
  float* const wgt    = (float*)(smem + 75776);

  const int t = threadIdx.x;           // 0..1023
  const int lane = t & 63;
  const int w = t >> 6;                // 0..15
  const int kg = w >> 3;               // K-group: chunks [kg*4, kg*4+4)
  const int ct_ = w & 7;               // col-tile
  const int l15 = lane & 15;
  const int lq = lane >> 4;
  const int n0 = blockIdx.x * 32;
  const int rx = (l15 & 7) << 4;

  // A staging: 1024 thr = 32 rows x 32 col-groups; pair {c, c+4} per iter.
  const int srow = t >> 5;             // 0..31
  const int scf = t & 31;              // fp32 cols scf*4 + j*128
  const float* ap = inp + (size_t)(n0 + srow) * 4096 + scf * 4;
  const int sx = (srow & 7) << 4;

  f32x4 accO[2] = {}, acc8[2] = {};
  float4 av[2][4];

  const uint4* wown = W1p + (size_t)(ct_ * 128) * 64 + lane;
  const uint4* w8b  = W1p + (size_t)(8 * 128) * 64 + lane;

  // ---- prologue: stage pair {0, 4}
#pragma unroll
  for (int g = 0; g < 2; ++g)
#pragma unroll
    for (int j = 0; j < 4; ++j)
      av[g][j] = *(const float4*)(ap + (size_t)(g * 4) * 512 + j * 128);
#pragma unroll
  for (int g = 0; g < 2; ++g) {
    char* d2 = Ab + g * 32768 + srow * 1024;
#pragma unroll
    for (int j = 0; j < 4; ++j) {
      uint2 u; u.x = pk2(av[g][j].x, av[g][j].y); u.y = pk2(av[g][j].z, av[g][j].w);
      *(uint2*)(d2 + ((scf * 8 + j * 256) ^ sx)) = u;
    }
  }
  __syncthreads();

  for (int c = 0; c < 4; ++c) {
    if (c < 3) {  // prefetch next pair {c+1, c+5} into registers
#pragma unroll
      for (int g = 0; g < 2; ++g)
#pragma unroll
        for (int j = 0; j < 4; ++j)
          av[g][j] = *(const float4*)(ap + (size_t)(g * 4 + c + 1) * 512 + j * 128);
    }
    const int ck = kg * 4 + c;         // this wave's K-chunk
    const char* A0 = Ab + kg * 32768;
#pragma unroll
    for (int ks = 0; ks < 16; ++ks) {
      bf16x8 b = __builtin_bit_cast(bf16x8, wown[(size_t)(ck * 16 + ks) * 64]);
      bf16x8 a0 = *(const bf16x8*)(A0 + l15 * 1024 + ((ks * 64 + lq * 16) ^ rx));
      bf16x8 a1 = *(const bf16x8*)(A0 + (16 + l15) * 1024 + ((ks * 64 + lq * 16) ^ rx));
      accO[0] = mfma16(a0, b, accO[0]);
      accO[1] = mfma16(a1, b, accO[1]);
    }
#pragma unroll
    for (int ii = 0; ii < 2; ++ii) {   // gating tile-8, ks split by col-tile
      const int ks8 = ct_ + ii * 8;
      bf16x8 b8 = __builtin_bit_cast(bf16x8, w8b[(size_t)(ck * 16 + ks8) * 64]);
      bf16x8 a0 = *(const bf16x8*)(A0 + l15 * 1024 + ((ks8 * 64 + lq * 16) ^ rx));
      bf16x8 a1 = *(const bf16x8*)(A0 + (16 + l15) * 1024 + ((ks8 * 64 + lq * 16) ^ rx));
      acc8[0] = mfma16(a0, b8, acc8[0]);
      acc8[1] = mfma16(a1, b8, acc8[1]);
    }
    if (c < 3) {
      LDS_BARRIER();                   // all reads of Ab done (lgkm only:
                                       // av global prefetch stays in flight)
#pragma unroll
      for (int g = 0; g < 2; ++g) {
        char* d2 = Ab + g * 32768 + srow * 1024;
#pragma unroll
        for (int j = 0; j < 4; ++j) {
          uint2 u; u.x = pk2(av[g][j].x, av[g][j].y); u.y = pk2(av[g][j].z, av[g][j].w);
          *(uint2*)(d2 + ((scf * 8 + j * 256) ^ sx)) = u;
        }
      }
    }
    LDS_BARRIER();                     // staged writes visible / final fence
  }

  // ---- reductions: accO pair-sum (w, w+8) + acc8 16-way (reuse A region)
  *(f32x4*)(Ab + (size_t)((w * 2 + 0) * 64 + lane) * 16) = accO[0];
  *(f32x4*)(Ab + (size_t)((w * 2 + 1) * 64 + lane) * 16) = accO[1];
  *(f32x4*)(Ab + 32768 + (size_t)((w * 2 + 0) * 64 + lane) * 16) = acc8[0];
  *(f32x4*)(Ab + 32768 + (size_t)((w * 2 + 1) * 64 + lane) * 16) = acc8[1];
  __syncthreads();
  f32x4 hO[2] = {};
  if (w < 8) {
#pragma unroll
    for (int tt = 0; tt < 2; ++tt) {
      f32x4 x = *(const f32x4*)(Ab + (size_t)((w * 2 + tt) * 64 + lane) * 16);
      f32x4 y = *(const f32x4*)(Ab + (size_t)(((w + 8) * 2 + tt) * 64 + lane) * 16);
#pragma unroll
      for (int r_ = 0; r_ < 4; ++r_) hO[tt][r_] = x[r_] + y[r_];
    }
  }
  if (t < 512) {  // gating scores: 32 tok x 16 cols
    const int tok = t >> 4, col = t & 15;
    const int tt = tok >> 4, lq_ = (tok >> 2) & 3, r_ = tok & 3;
    float sv = 0.f;
#pragma unroll
    for (int w2 = 0; w2 < 16; ++w2)
      sv += *(const float*)(Ab + 32768 +
            (size_t)((w2 * 2 + tt) * 64 + lq_ * 16 + col) * 16 + r_ * 4);
    scores[tok * 16 + col] = sv;
  }
  __syncthreads();
  if (t < 32) {
    float l_[9];
#pragma unroll
    for (int e = 0; e < 9; ++e) l_[e] = scores[t * 16 + e];
    float mx = -3.4e38f;
#pragma unroll
    for (int e = 0; e < 8; ++e) { l_[e] += rb[e]; mx = fmaxf(mx, l_[e]); }
    float g[8], s = 0.f;
#pragma unroll
    for (int e = 0; e < 8; ++e) { g[e] = __expf(l_[e] - mx); s += g[e]; }
    const float thr = 0.125f / (1.f + __expf(-(l_[8] + tb[0])));
    const float inv = 1.f / s;
    float wv[8], ws = 0.f;
#pragma unroll
    for (int e = 0; e < 8; ++e) { wv[e] = fmaxf(g[e] * inv - thr, 0.f); ws += wv[e]; }
    const float wn = (ws == 0.f) ? 1.f : ws;
#pragma unroll
    for (int e = 0; e < 8; ++e) wgt[t * 8 + e] = wv[e] / wn;
  }
  __syncthreads();
  // weighted h -> whl (wave w<8 == expert w), swizzled by token
  if (w < 8) {
#pragma unroll
    for (int tt = 0; tt < 2; ++tt)
#pragma unroll
      for (int r_ = 0; r_ < 4; ++r_) {
        const int tok = tt * 16 + lq * 4 + r_;
        *(unsigned short*)(whl + tok * 256 + (((w * 16 + l15) * 2) ^ ((tok & 7) << 4))) =
            (unsigned short)bfbits(hO[tt][r_] * wgt[tok * 8 + w]);
      }
  }
  __syncthreads();
  // coalesced wh write: rows copied byte-verbatim (swizzle kept; n0%32==0)
  if (t < 512) {
    const int row = t >> 4, seg = t & 15;
    ((uint4*)(wh + (size_t)(n0 + row) * 128))[seg] =
        ((const uint4*)(whl + row * 256))[seg];
  }
}

// ---------------- k2_out: out[256 tok][128 col] per block, grid 1024, 512
// thr. B2p slice staged once to LDS; swizzled Ob bounce -> 128B-contiguous
// nontemporal stores; bounce barriers lgkm-only so stores keep streaming.
__global__ __launch_bounds__(512, 4) void k2_out(
    const unsigned short* __restrict__ wh, const uint4* __restrict__ B2p,
    float* __restrict__ out) {
  __shared__ __align__(16) char Bl[32768];
  __shared__ __align__(16) char Ob[32768];
  const int t = threadIdx.x, lane = t & 63, w = t >> 6;
  const int l15 = lane & 15, lq = lane >> 4;
  const int bid = blockIdx.x;
  const int tokg = bid >> 5, colg = bid & 31;
  const int n0 = tokg * 256, c0 = colg * 128;

  {  // stage B slice: 8 ct x 4 ks x 64 lanes x 16B = 32 KB, linear
    const uint4* src = B2p + (size_t)(colg * 32) * 64;
#pragma unroll
    for (int i = 0; i < 4; ++i)
      __builtin_amdgcn_global_load_lds((gp_t)(const void*)(src + i * 512 + t),
          (lp_t)(void*)(Bl + (i * 512 + w * 64) * 16), 16, 0, 0);
  }
  __syncthreads();  // vmcnt drain required (global_load_lds) — keep full sync

  const int srow = t >> 3, sseg = t & 7;       // store map: 64 rows x 8 segs
  const int swz = (srow & 7) << 4;

#pragma unroll
  for (int tt = 0; tt < 2; ++tt) {
    const int tok = n0 + tt * 128 + w * 16 + l15;
    bf16x8 pa[4];
    const uint4* whu = (const uint4*)wh + (size_t)tok * 16;
#pragma unroll
    for (int ks = 0; ks < 4; ++ks)
      pa[ks] = __builtin_bit_cast(bf16x8, whu[(ks * 4 + lq) ^ (l15 & 7)]);
    f32x4 acc[8] = {};
#pragma unroll
    for (int ct = 0; ct < 8; ++ct)
#pragma unroll
      for (int ks = 0; ks < 4; ++ks) {
        bf16x8 b = *(const bf16x8*)(Bl + (size_t)((ct * 4 + ks) * 64 + lane) * 16);
        acc[ct] = mfma16(b, pa[ks], acc[ct]);  // swapped: 4 consecutive cols/lane
      }
#pragma unroll
    for (int sr = 0; sr < 2; ++sr) {
      if ((w >> 2) == sr) {
        const int tl = (w & 3) * 16 + l15;     // 0..63
        char* d = Ob + tl * 512;
#pragma unroll
        for (int ct = 0; ct < 8; ++ct)
          *(f32x4*)(d + ((ct * 64 + lq * 16) ^ ((tl & 7) << 4))) = acc[ct];
      }
      LDS_BARRIER();                           // Ob writes visible; global
                                               // stores keep streaming
      {
        float* op = out + (size_t)(n0 + tt * 128 + sr * 64 + srow) * 4096 + c0 + sseg * 4;
#pragma unroll
        for (int j = 0; j < 4; ++j) {
          f32x4 v = *(const f32x4*)(Ob + srow * 512 + ((sseg * 16 + j * 128) ^ swz));
          __builtin_nontemporal_store(v, (f32x4*)(op + j * 32));
        }
      }
      LDS_BARRIER();                           // Ob reads done before overwrite
    }
  }
}

extern "C" void kernel_launch(void* const* d_in, const int* in_sizes, int n_in,
                              void* d_out, int out_size, void* d_ws, size_t ws_size,
                              hipStream_t stream) {
  (void)in_sizes; (void)n_in; (void)out_size; (void)ws_size;
  const float* inp      = (const float*)d_in[0];
  const float* router_w = (const float*)d_in[1];
  const float* router_b = (const float*)d_in[2];
  const float* thr_w    = (const float*)d_in[3];
  const float* thr_b    = (const float*)d_in[4];
  const float* lora_A   = (const float*)d_in[5];
  const float* lora_B   = (const float*)d_in[6];
  float* out = (float*)d_out;

  char* ws = (char*)d_ws;
  uint4*          W1p = (uint4*)ws;                                // 1,179,648 B
  uint4*          B2p = (uint4*)(ws + 1179648);                    // 1,048,576 B
  unsigned short* wh  = (unsigned short*)(ws + 1179648 + 1048576); // 2,097,152 B

  pack_all<<<544, 256, 0, stream>>>(router_w, thr_w, lora_A, lora_B, W1p, B2p);
  k1_gate<<<256, 1024, 0, stream>>>(inp, W1p, router_b, thr_b, wh);
  k2_out<<<1024, 512, 0, stream>>>(wh, B2p, out);
}